// Round 9
// baseline (298.545 us; speedup 1.0000x reference)
//
#include <hip/hip_runtime.h>
#include <hip/hip_bf16.h>

typedef __attribute__((ext_vector_type(8))) short short8;
typedef __attribute__((ext_vector_type(4))) float f32x4;
typedef __attribute__((ext_vector_type(4))) unsigned uintx4;

#define B_  32
#define S_  484
#define E_  1024
#define NH  16
#define SP  512          // padded sequence length
#define M_  (B_*S_)      // 15488 = 121*128 = 60.5*256

static __device__ __forceinline__ ushort f2bf(float f) {
  union { float f; unsigned u; } v; v.f = f;
  unsigned u = v.u;
  return (ushort)((u + 0x7FFFu + ((u >> 16) & 1u)) >> 16);
}

static __device__ __forceinline__ unsigned cvt_pk_bf16(float lo, float hi) {
  unsigned r;
  asm("v_cvt_pk_bf16_f32 %0, %1, %2" : "=v"(r) : "v"(lo), "v"(hi));
  return r;
}

#define GLOAD_LDS16(gp, lp) \
  __builtin_amdgcn_global_load_lds((const __attribute__((address_space(1))) void*)(gp), \
                                   (__attribute__((address_space(3))) void*)(lp), 16, 0, 0)

// ---------------- f32 -> bf16 flat convert (vectorized) ----------------
__global__ __launch_bounds__(256)
void cvt_f32_bf16(const float* __restrict__ x, ushort* __restrict__ y, int n4) {
  int i = blockIdx.x * 256 + threadIdx.x;
  int stride = gridDim.x * 256;
  for (; i < n4; i += stride) {
    float4 v = ((const float4*)x)[i];
    ushort4 h;
    h.x = f2bf(v.x); h.y = f2bf(v.y); h.z = f2bf(v.z); h.w = f2bf(v.w);
    ((ushort4*)y)[i] = h;
  }
}

// ---------------- weight transpose + convert: WT[n][k] = W[k][n] ----------------
__global__ __launch_bounds__(256)
void transpose_convert(const float* __restrict__ W, ushort* __restrict__ WT, int K, int N) {
  __shared__ float tile[32][33];
  int k0 = blockIdx.y * 32, n0 = blockIdx.x * 32;
  int tx = threadIdx.x, ty = threadIdx.y;   // 32 x 8
  for (int i = ty; i < 32; i += 8) tile[i][tx] = W[(size_t)(k0 + i) * N + n0 + tx];
  __syncthreads();
  for (int i = ty; i < 32; i += 8) WT[(size_t)(n0 + i) * K + k0 + tx] = f2bf(tile[tx][i]);
}

// ======== counted-vmcnt GEMM: 256x256 tile, 512 thr, 3-buffer depth-2 ========
// T4: vmcnt(4) steady state (stage kt+1 stays in flight across the barrier).
// XCD-chunked 1D grid (244 blocks): 4 n-blocks of each m-slab on one XCD.
// M tail: clamp-load rows to M_-1, guard stores.
// EPI 0: bf16 out (scaled), ((b*NH+h)*SP + pos)*64 + (n&63)    (qp)
// EPI 2: f32 out, row-major [M][1024]                          (d_out)
template<int EPI>
__global__ __launch_bounds__(512)
void gemm_cnt256(const ushort* __restrict__ A, const ushort* __restrict__ BT,
                 void* __restrict__ Cout, float oscale) {
  const int K = 1024, N = 1024, NK = 32;
  __shared__ alignas(16) ushort sA[3][256 * 32];
  __shared__ alignas(16) ushort sB[3][256 * 32];
  const int tid = threadIdx.x;
  const int lane = tid & 63, w = tid >> 6;        // 8 waves

  // chunked bijective XCD map (nwg = 244: qq=30, rr=4)
  const int nwg = gridDim.x;
  const int qq = nwg >> 3, rr = nwg & 7;
  const int x = blockIdx.x & 7, seq = blockIdx.x >> 3;
  const int logical = x * qq + (x < rr ? x : rr) + seq;
  const int m0 = (logical >> 2) * 256;            // 61 m-tiles
  const int n0 = (logical & 3) * 256;             // 4 n-tiles

  // staging: 4 threads/row (32 ushorts), 2 issues per array cover 256 rows
  const int brow = tid >> 2, bcol = (tid & 3) * 8;
  const int rowA0 = min(m0 + brow, M_ - 1);
  const int rowA1 = min(m0 + brow + 128, M_ - 1);
  const ushort* gA0 = A + (size_t)rowA0 * K + bcol;
  const ushort* gA1 = A + (size_t)rowA1 * K + bcol;
  const ushort* gB0 = BT + (size_t)(n0 + brow) * K + bcol;
  const int dst = tid * 8;                        // ushort idx; +4096 = +128 rows

  const int wr = w >> 2, wc = w & 3;              // 2x4 wave grid, each 128x64
  const int g4 = lane >> 4, l16 = lane & 15;

  f32x4 acc[8][4] = {};

  auto stage = [&](int kt, int buf) {             // 4 vmem ops/thread
    GLOAD_LDS16(gA0 + kt * 32,           &sA[buf][dst]);
    GLOAD_LDS16(gA1 + kt * 32,           &sA[buf][dst + 4096]);
    GLOAD_LDS16(gB0 + kt * 32,           &sB[buf][dst]);
    GLOAD_LDS16(gB0 + kt * 32 + 128 * K, &sB[buf][dst + 4096]);
  };

  stage(0, 0);
  stage(1, 1);

  int cur = 0;
  for (int kt = 0; kt < NK; ++kt) {
    if (kt + 1 < NK) asm volatile("s_waitcnt vmcnt(4)" ::: "memory");
    else             asm volatile("s_waitcnt vmcnt(0)" ::: "memory");
    asm volatile("s_waitcnt lgkmcnt(0)" ::: "memory");
    __builtin_amdgcn_s_barrier();
    if (kt + 2 < NK) {
      int nb = cur + 2; if (nb >= 3) nb -= 3;
      stage(kt + 2, nb);
    }
    const ushort* pa = &sA[cur][(wr * 128 + l16) * 32 + 8 * g4];
    const ushort* pb = &sB[cur][(wc * 64 + l16) * 32 + 8 * g4];
    short8 af[8], bf[4];
#pragma unroll
    for (int i = 0; i < 8; ++i) af[i] = *(const short8*)(pa + i * 16 * 32);
#pragma unroll
    for (int i = 0; i < 4; ++i) bf[i] = *(const short8*)(pb + i * 16 * 32);
#pragma unroll
    for (int mi = 0; mi < 8; ++mi)
#pragma unroll
      for (int ni = 0; ni < 4; ++ni)
        acc[mi][ni] = __builtin_amdgcn_mfma_f32_16x16x32_bf16(af[mi], bf[ni], acc[mi][ni], 0, 0, 0);
    if (++cur >= 3) cur = 0;
  }

#pragma unroll
  for (int mi = 0; mi < 8; ++mi) {
#pragma unroll
    for (int ni = 0; ni < 4; ++ni) {
#pragma unroll
      for (int r = 0; r < 4; ++r) {
        int m = m0 + wr * 128 + mi * 16 + g4 * 4 + r;
        int n = n0 + wc * 64 + ni * 16 + l16;
        if (m < M_) {
          float vv = acc[mi][ni][r];
          if (EPI == 2) {
            ((float*)Cout)[(size_t)m * N + n] = vv;
          } else {
            int b = m / S_, pos = m % S_;
            ushort hv = f2bf(vv * oscale);
            ((ushort*)Cout)[(((size_t)b * NH + (n >> 6)) * SP + pos) * 64 + (n & 63)] = hv;
          }
        }
      }
    }
  }
}

// ---------------- 128x128 GEMM (K/V projections), f32 A reg-staged ----------------
// EPI 0: bf16 out (scaled), ((b*HN+h)*SP + pos)*64 + d   [SWZ: d ^= (pos&7)<<3]
// EPI 1: bf16 out (V), ((b*HN+h)*64 + d)*SP + permuted pos [SWZ: sigma + granule xor]
template<int EPI, int SWZ, int NXLOG>
__global__ __launch_bounds__(256)
void gemm_bt(const float* __restrict__ Ain, const ushort* __restrict__ BT,
             void* __restrict__ Cout, int N, int K, int HN, float oscale) {
  __shared__ alignas(16) ushort sA[2][128 * 32];
  __shared__ alignas(16) ushort sB[2][128 * 32];
  const int tid = threadIdx.x;
  const int lane = tid & 63, w = tid >> 6;

  const int nwg = gridDim.x;
  const int qq = nwg >> 3, rr = nwg & 7;
  const int x = blockIdx.x & 7, seq = blockIdx.x >> 3;
  const int logical = x * qq + (x < rr ? x : rr) + seq;
  const int m0 = (logical >> NXLOG) * 128;
  const int n0 = (logical & ((1 << NXLOG) - 1)) * 128;
  const int NK = K >> 5;

  const int srow = w * 32 + (lane >> 2);
  const int scol = (lane & 3) * 8;
  const ushort* gB0 = BT + (size_t)(n0 + srow) * K + scol;

  const int arow = w * 32 + (lane >> 1);
  const int acol = (lane & 1) * 16;
  const float* gA0f = Ain + (size_t)(m0 + arow) * K + acol;

  const int wr = w >> 1, wc = w & 1;
  const int g4 = lane >> 4, l16 = lane & 15;
  const int aoff = (wr * 64 + l16) * 32 + 8 * g4;
  const int boff = (wc * 64 + l16) * 32 + 8 * g4;

  f32x4 acc[4][4] = {};
  float4 fA0, fA1, fA2, fA3;

  auto issueA = [&](int kt) {
    const float4* p = (const float4*)(gA0f + kt * 32);
    fA0 = p[0]; fA1 = p[1]; fA2 = p[2]; fA3 = p[3];
  };
  auto writeA = [&](int buf) {
    unsigned d0 = cvt_pk_bf16(fA0.x, fA0.y), d1 = cvt_pk_bf16(fA0.z, fA0.w);
    unsigned d2 = cvt_pk_bf16(fA1.x, fA1.y), d3 = cvt_pk_bf16(fA1.z, fA1.w);
    unsigned d4 = cvt_pk_bf16(fA2.x, fA2.y), d5 = cvt_pk_bf16(fA2.z, fA2.w);
    unsigned d6 = cvt_pk_bf16(fA3.x, fA3.y), d7 = cvt_pk_bf16(fA3.z, fA3.w);
    ushort* dstp = &sA[buf][arow * 32 + acol];
    uintx4 q0 = {d0, d1, d2, d3}, q1 = {d4, d5, d6, d7};
    *(uintx4*)dstp = q0;
    *(uintx4*)(dstp + 8) = q1;
  };

  issueA(0);
  GLOAD_LDS16(gB0,          &sB[0][(w * 32) * 32]);
  GLOAD_LDS16(gB0 + 16 * K, &sB[0][(w * 32 + 16) * 32]);
  writeA(0);

  for (int kt = 0; kt < NK; ++kt) {
    __syncthreads();
    const int nb = (kt + 1) & 1;
    if (kt + 1 < NK) {
      const ushort* gb = gB0 + (kt + 1) * 32;
      GLOAD_LDS16(gb,          &sB[nb][(w * 32) * 32]);
      GLOAD_LDS16(gb + 16 * K, &sB[nb][(w * 32 + 16) * 32]);
      issueA(kt + 1);
    }
    const ushort* pa = &sA[kt & 1][aoff];
    const ushort* pb = &sB[kt & 1][boff];
    short8 af[4], bf[4];
#pragma unroll
    for (int i = 0; i < 4; ++i) {
      af[i] = *(const short8*)(pa + i * 16 * 32);
      bf[i] = *(const short8*)(pb + i * 16 * 32);
    }
#pragma unroll
    for (int mi = 0; mi < 4; ++mi)
#pragma unroll
      for (int ni = 0; ni < 4; ++ni)
        acc[mi][ni] = __builtin_amdgcn_mfma_f32_16x16x32_bf16(af[mi], bf[ni], acc[mi][ni], 0, 0, 0);
    if (kt + 1 < NK) writeA(nb);
  }

#pragma unroll
  for (int mi = 0; mi < 4; ++mi) {
#pragma unroll
    for (int ni = 0; ni < 4; ++ni) {
#pragma unroll
      for (int r = 0; r < 4; ++r) {
        int m = m0 + wr * 64 + mi * 16 + g4 * 4 + r;
        int n = n0 + wc * 64 + ni * 16 + l16;
        float vv = acc[mi][ni][r];
        int b = m / S_, pos = m % S_;
        if (EPI == 0) {
          int dd = n & 63;
          if (SWZ) dd ^= (pos & 7) << 3;      // K-LDS row bank swizzle
          ushort hv = f2bf(vv * oscale);
          ((ushort*)Cout)[(((size_t)b * HN + (n >> 6)) * SP + pos) * 64 + dd] = hv;
        } else {
          int local = pos & 31;
          int j = (local < 16) ? (2 * local) : (2 * local - 31);
          int pf_ = (pos & ~31) | (j ^ ((n & 3) << 3));   // sigma + granule bank swizzle
          ushort hv = f2bf(vv);
          ((ushort*)Cout)[(((size_t)b * HN + (n >> 6)) * 64 + (n & 63)) * SP + pf_] = hv;
        }
      }
    }
  }
}

// ---------------- fused GQA attention: LDS-staged K/V, packed P path ----------------
__global__ __launch_bounds__(256)
void attn_kernel(const ushort* __restrict__ qp, const ushort* __restrict__ kp,
                 const ushort* __restrict__ vpT, const float* __restrict__ rel,
                 ushort* __restrict__ ao) {
  __shared__ float sBias[1056];                   // +32 guard offset
  __shared__ alignas(16) ushort sK[2][32 * 64];
  __shared__ alignas(16) ushort sV[2][64 * 32];
  __shared__ alignas(16) ushort sP[4][16 * 40];
  const int tid = threadIdx.x;
  const int blk = blockIdx.x;
  const int logical = (blk & 7) * 512 + (blk >> 3);     // bijective (4096 = 8*512)
  const int qt = logical & 7, head = (logical >> 3) & 15, b = logical >> 7;
  const int g = head >> 2;
  const float LOG2E = 1.44269504f;
  for (int t = tid; t < 1056; t += 256)
    sBias[t] = (t >= 32 && t < 999) ? rel[(t - 32) * 16 + head] * LOG2E : -1e30f;

  const int lane = tid & 63, w = tid >> 6;
  const int g4 = lane >> 4, l16 = lane & 15;
  const int qw = qt * 64 + w * 16;

  const ushort* qbase = qp + (((size_t)b * NH + head) * SP + qw + l16) * 64;
  short8 qf0 = *(const short8*)(qbase + 8 * g4);
  short8 qf1 = *(const short8*)(qbase + 32 + 8 * g4);

  const ushort* kSrc = kp  + ((size_t)b * 4 + g) * SP * 64 + (tid >> 3) * 64 + (tid & 7) * 8;
  const ushort* vSrc = vpT + ((size_t)b * 4 + g) * 64 * SP + (tid >> 2) * SP + (tid & 3) * 8;

  f32x4 acc[4] = {};
  float ps[4] = {0.f, 0.f, 0.f, 0.f};
  const int ib = l16 - (qw + g4 * 4) + 483 + 32;
  ushort* sPw = &sP[w][0];

  const int kswz  = (l16 & 7) << 3;
  const int kOff0 = l16 * 64 + ((8 * g4) ^ kswz);
  const int kOff1 = l16 * 64 + ((32 + 8 * g4) ^ kswz);
  const int vOff  = l16 * 32 + 8 * (g4 ^ (l16 & 3));

  GLOAD_LDS16(kSrc, &sK[0][w * 512]);
  GLOAD_LDS16(vSrc, &sV[0][w * 512]);

  for (int kt = 0; kt < 16; ++kt) {
    __syncthreads();
    if (kt + 1 < 16) {
      GLOAD_LDS16(kSrc + (kt + 1) * 2048, &sK[(kt + 1) & 1][w * 512]);
      GLOAD_LDS16(vSrc + (kt + 1) * 32,   &sV[(kt + 1) & 1][w * 512]);
    }
    const ushort* sk = &sK[kt & 1][0];
    const ushort* sv = &sV[kt & 1][0];
    short8 kf0 = *(const short8*)(sk + kOff0);
    short8 kf1 = *(const short8*)(sk + kOff1);
    short8 kf2 = *(const short8*)(sk + 1024 + kOff0);
    short8 kf3 = *(const short8*)(sk + 1024 + kOff1);
    f32x4 s0 = {}, s1 = {};
    s0 = __builtin_amdgcn_mfma_f32_16x16x32_bf16(qf0, kf0, s0, 0, 0, 0);
    s0 = __builtin_amdgcn_mfma_f32_16x16x32_bf16(qf1, kf1, s0, 0, 0, 0);
    s1 = __builtin_amdgcn_mfma_f32_16x16x32_bf16(qf0, kf2, s1, 0, 0, 0);
    s1 = __builtin_amdgcn_mfma_f32_16x16x32_bf16(qf1, kf3, s1, 0, 0, 0);

    const int k0 = kt * 32;
#pragma unroll
    for (int r = 0; r < 4; ++r) {
      int i0 = ib + k0 - r;
      float p0 = __builtin_amdgcn_exp2f(s0[r] + sBias[i0]);
      float p1 = __builtin_amdgcn_exp2f(s1[r] + sBias[i0 + 16]);
      if (kt == 15) {                       // mask BEFORE store: pad P == 0 exactly
        p0 = (k0 + l16 < S_) ? p0 : 0.f;
        p1 = (k0 + 16 + l16 < S_) ? p1 : 0.f;
      }
      ps[r] += p0 + p1;
      *(unsigned*)(sPw + (g4 * 4 + r) * 40 + 2 * l16) = cvt_pk_bf16(p0, p1);
    }
    short8 pf = *(const short8*)(sPw + l16 * 40 + 8 * g4);
#pragma unroll
    for (int nt = 0; nt < 4; ++nt) {
      short8 vf = *(const short8*)(sv + vOff + nt * 512);
      acc[nt] = __builtin_amdgcn_mfma_f32_16x16x32_bf16(pf, vf, acc[nt], 0, 0, 0);
    }
  }

#pragma unroll
  for (int off = 1; off < 16; off <<= 1) {
#pragma unroll
    for (int r = 0; r < 4; ++r) ps[r] += __shfl_xor(ps[r], off, 64);
  }

#pragma unroll
  for (int r = 0; r < 4; ++r) {
    int q_abs = qw + g4 * 4 + r;
    if (q_abs < S_) {
      float inv = 1.f / ps[r];
#pragma unroll
      for (int nt = 0; nt < 4; ++nt) {
        int dd = nt * 16 + l16;
        ao[((size_t)b * S_ + q_abs) * 1024 + head * 64 + dd] = f2bf(acc[nt][r] * inv);
      }
    }
  }
}

extern "C" void kernel_launch(void* const* d_in, const int* in_sizes, int n_in,
                              void* d_out, int out_size, void* d_ws, size_t ws_size,
                              hipStream_t stream) {
  const float* query = (const float*)d_in[0];
  const float* key   = (const float*)d_in[1];
  const float* value = (const float*)d_in[2];
  const float* Wq    = (const float*)d_in[3];
  const float* Wk    = (const float*)d_in[4];
  const float* Wv    = (const float*)d_in[5];
  const float* Wo    = (const float*)d_in[6];
  const float* rel   = (const float*)d_in[7];

  char* ws = (char*)d_ws;
  size_t off = 0;
  auto alloc = [&](size_t bytes) { char* p = ws + off; off += (bytes + 255) & ~(size_t)255; return p; };

  const size_t MEelems = (size_t)M_ * E_;             // 15,859,712
  ushort* qb  = (ushort*)alloc(MEelems * 2);          // query in bf16
  ushort* wqT = (ushort*)alloc((size_t)1024 * 1024 * 2);
  ushort* wkT = (ushort*)alloc((size_t)256 * 1024 * 2);
  ushort* wvT = (ushort*)alloc((size_t)256 * 1024 * 2);
  ushort* woT = (ushort*)alloc((size_t)1024 * 1024 * 2);
  ushort* qp  = (ushort*)alloc((size_t)B_ * NH * SP * 64 * 2);   // 32 MB
  ushort* kp  = (ushort*)alloc((size_t)B_ * 4 * SP * 64 * 2);    // 8 MB
  ushort* vp  = (ushort*)alloc((size_t)B_ * 4 * 64 * SP * 2);    // 8 MB
  ushort* ao  = (ushort*)alloc(MEelems * 2);

  cvt_f32_bf16<<<2048, 256, 0, stream>>>(query, qb, (int)(MEelems / 4));

  transpose_convert<<<dim3(32, 32), dim3(32, 8), 0, stream>>>(Wq, wqT, 1024, 1024);
  transpose_convert<<<dim3(8, 32),  dim3(32, 8), 0, stream>>>(Wk, wkT, 1024, 256);
  transpose_convert<<<dim3(8, 32),  dim3(32, 8), 0, stream>>>(Wv, wvT, 1024, 256);
  transpose_convert<<<dim3(32, 32), dim3(32, 8), 0, stream>>>(Wo, woT, 1024, 1024);

  const float QSCALE = 0.125f * 1.44269504f;   // fold 1/sqrt(D) and log2e into q
  gemm_cnt256<0><<<244, 512, 0, stream>>>(qb, wqT, qp, QSCALE);
  gemm_bt<0,1,1><<<242, 256, 0, stream>>>(key,   wkT, kp, 256, 1024, 4, 1.0f);
  gemm_bt<1,1,1><<<242, 256, 0, stream>>>(value, wvT, vp, 256, 1024, 4, 1.0f);

  attn_kernel<<<4096, 256, 0, stream>>>(qp, kp, vp, rel, ao);

  gemm_cnt256<2><<<244, 512, 0, stream>>>(ao, woT, d_out, 1.0f);
}

// Round 10
// 297.190 us; speedup vs baseline: 1.0046x; 1.0046x over previous
//
#include <hip/hip_runtime.h>
#include <hip/hip_bf16.h>

typedef __attribute__((ext_vector_type(8))) short short8;
typedef __attribute__((ext_vector_type(4))) float f32x4;
typedef __attribute__((ext_vector_type(4))) unsigned uintx4;

#define B_  32
#define S_  484
#define E_  1024
#define NH  16
#define SP  512          // padded sequence length
#define M_  (B_*S_)      // 15488 = 121*128 = 60.5*256

static __device__ __forceinline__ ushort f2bf(float f) {
  union { float f; unsigned u; } v; v.f = f;
  unsigned u = v.u;
  return (ushort)((u + 0x7FFFu + ((u >> 16) & 1u)) >> 16);
}

static __device__ __forceinline__ unsigned cvt_pk_bf16(float lo, float hi) {
  unsigned r;
  asm("v_cvt_pk_bf16_f32 %0, %1, %2" : "=v"(r) : "v"(lo), "v"(hi));
  return r;
}

#define GLOAD_LDS16(gp, lp) \
  __builtin_amdgcn_global_load_lds((const __attribute__((address_space(1))) void*)(gp), \
                                   (__attribute__((address_space(3))) void*)(lp), 16, 0, 0)

// ---------------- f32 -> bf16 flat convert (vectorized) ----------------
__global__ __launch_bounds__(256)
void cvt_f32_bf16(const float* __restrict__ x, ushort* __restrict__ y, int n4) {
  int i = blockIdx.x * 256 + threadIdx.x;
  int stride = gridDim.x * 256;
  for (; i < n4; i += stride) {
    float4 v = ((const float4*)x)[i];
    ushort4 h;
    h.x = f2bf(v.x); h.y = f2bf(v.y); h.z = f2bf(v.z); h.w = f2bf(v.w);
    ((ushort4*)y)[i] = h;
  }
}

// ---------------- weight transpose + convert: WT[n][k] = W[k][n] ----------------
__global__ __launch_bounds__(256)
void transpose_convert(const float* __restrict__ W, ushort* __restrict__ WT, int K, int N) {
  __shared__ float tile[32][33];
  int k0 = blockIdx.y * 32, n0 = blockIdx.x * 32;
  int tx = threadIdx.x, ty = threadIdx.y;   // 32 x 8
  for (int i = ty; i < 32; i += 8) tile[i][tx] = W[(size_t)(k0 + i) * N + n0 + tx];
  __syncthreads();
  for (int i = ty; i < 32; i += 8) WT[(size_t)(n0 + i) * K + k0 + tx] = f2bf(tile[tx][i]);
}

// ======== counted-vmcnt GEMM: 256x256 tile, 512 thr, 3-buffer depth-2 ========
// T4: vmcnt(4) steady state. T2: LDS granule XOR swizzle (row>>1)&3 —
// linear LDS dest + pre-swizzled GLOBAL source col (rule #21), fragment reads
// XOR granule; XOR term folds to (l16>>1)&3 (row-block-independent).
// XCD-chunked 1D grid (244 blocks). M tail clamp-load + guard-store.
// EPI 0: bf16 out (scaled), ((b*NH+h)*SP + pos)*64 + (n&63)    (qp)
// EPI 2: f32 out, row-major [M][1024]                          (d_out)
template<int EPI>
__global__ __launch_bounds__(512)
void gemm_cnt256(const ushort* __restrict__ A, const ushort* __restrict__ BT,
                 void* __restrict__ Cout, float oscale) {
  const int K = 1024, N = 1024, NK = 32;
  __shared__ alignas(16) ushort sA[3][256 * 32];
  __shared__ alignas(16) ushort sB[3][256 * 32];
  const int tid = threadIdx.x;
  const int lane = tid & 63, w = tid >> 6;        // 8 waves

  // chunked bijective XCD map (nwg = 244: qq=30, rr=4)
  const int nwg = gridDim.x;
  const int qq = nwg >> 3, rr = nwg & 7;
  const int x = blockIdx.x & 7, seq = blockIdx.x >> 3;
  const int logical = x * qq + (x < rr ? x : rr) + seq;
  const int m0 = (logical >> 2) * 256;            // 61 m-tiles
  const int n0 = (logical & 3) * 256;             // 4 n-tiles

  // staging: 4 threads/row; source col pre-swizzled so LDS granule g holds
  // logical granule g ^ ((row>>1)&3)   [row = tid>>2; (row>>1)&3 = (tid>>3)&3]
  const int brow = tid >> 2;
  const int scol = (((tid & 3) ^ ((tid >> 3) & 3))) * 8;
  const int rowA0 = min(m0 + brow, M_ - 1);
  const int rowA1 = min(m0 + brow + 128, M_ - 1);
  const ushort* gA0 = A + (size_t)rowA0 * K + scol;
  const ushort* gA1 = A + (size_t)rowA1 * K + scol;
  const ushort* gB0 = BT + (size_t)(n0 + brow) * K + scol;
  const int dst = tid * 8;                        // linear LDS dest (granule tid&3)

  const int wr = w >> 2, wc = w & 3;              // 2x4 wave grid, each 128x64
  const int g4 = lane >> 4, l16 = lane & 15;
  const int rs = (l16 >> 1) & 3;                  // folded read-swizzle term

  f32x4 acc[8][4] = {};

  auto stage = [&](int kt, int buf) {             // 4 vmem ops/thread
    GLOAD_LDS16(gA0 + kt * 32,           &sA[buf][dst]);
    GLOAD_LDS16(gA1 + kt * 32,           &sA[buf][dst + 4096]);
    GLOAD_LDS16(gB0 + kt * 32,           &sB[buf][dst]);
    GLOAD_LDS16(gB0 + kt * 32 + 128 * K, &sB[buf][dst + 4096]);
  };

  stage(0, 0);
  stage(1, 1);

  int cur = 0;
  for (int kt = 0; kt < NK; ++kt) {
    if (kt + 1 < NK) asm volatile("s_waitcnt vmcnt(4)" ::: "memory");
    else             asm volatile("s_waitcnt vmcnt(0)" ::: "memory");
    asm volatile("s_waitcnt lgkmcnt(0)" ::: "memory");
    __builtin_amdgcn_s_barrier();
    if (kt + 2 < NK) {
      int nb = cur + 2; if (nb >= 3) nb -= 3;
      stage(kt + 2, nb);
    }
    const ushort* pa = &sA[cur][(wr * 128 + l16) * 32 + 8 * (g4 ^ rs)];
    const ushort* pb = &sB[cur][(wc * 64 + l16) * 32 + 8 * (g4 ^ rs)];
    short8 af[8], bf[4];
#pragma unroll
    for (int i = 0; i < 8; ++i) af[i] = *(const short8*)(pa + i * 16 * 32);
#pragma unroll
    for (int i = 0; i < 4; ++i) bf[i] = *(const short8*)(pb + i * 16 * 32);
#pragma unroll
    for (int mi = 0; mi < 8; ++mi)
#pragma unroll
      for (int ni = 0; ni < 4; ++ni)
        acc[mi][ni] = __builtin_amdgcn_mfma_f32_16x16x32_bf16(af[mi], bf[ni], acc[mi][ni], 0, 0, 0);
    if (++cur >= 3) cur = 0;
  }

#pragma unroll
  for (int mi = 0; mi < 8; ++mi) {
#pragma unroll
    for (int ni = 0; ni < 4; ++ni) {
#pragma unroll
      for (int r = 0; r < 4; ++r) {
        int m = m0 + wr * 128 + mi * 16 + g4 * 4 + r;
        int n = n0 + wc * 64 + ni * 16 + l16;
        if (m < M_) {
          float vv = acc[mi][ni][r];
          if (EPI == 2) {
            ((float*)Cout)[(size_t)m * N + n] = vv;
          } else {
            int b = m / S_, pos = m % S_;
            ushort hv = f2bf(vv * oscale);
            ((ushort*)Cout)[(((size_t)b * NH + (n >> 6)) * SP + pos) * 64 + (n & 63)] = hv;
          }
        }
      }
    }
  }
}

// ---------------- 128x128 GEMM (K/V projections), f32 A reg-staged ----------------
// T2 swizzle: B via pre-swizzled global source; A via swizzled ds_write granules.
// EPI 0: bf16 out (scaled), ((b*HN+h)*SP + pos)*64 + d   [SWZ: d ^= (pos&7)<<3]
// EPI 1: bf16 out (V), ((b*HN+h)*64 + d)*SP + permuted pos [SWZ: sigma + granule xor]
template<int EPI, int SWZ, int NXLOG>
__global__ __launch_bounds__(256)
void gemm_bt(const float* __restrict__ Ain, const ushort* __restrict__ BT,
             void* __restrict__ Cout, int N, int K, int HN, float oscale) {
  __shared__ alignas(16) ushort sA[2][128 * 32];
  __shared__ alignas(16) ushort sB[2][128 * 32];
  const int tid = threadIdx.x;
  const int lane = tid & 63, w = tid >> 6;

  const int nwg = gridDim.x;
  const int qq = nwg >> 3, rr = nwg & 7;
  const int x = blockIdx.x & 7, seq = blockIdx.x >> 3;
  const int logical = x * qq + (x < rr ? x : rr) + seq;
  const int m0 = (logical >> NXLOG) * 128;
  const int n0 = (logical & ((1 << NXLOG) - 1)) * 128;
  const int NK = K >> 5;

  // B staging: row = w*32 + (lane>>2), granule = lane&3; swizzle source col
  const int srow = w * 32 + (lane >> 2);
  const int scol = ((lane & 3) ^ ((lane >> 3) & 3)) * 8;
  const ushort* gB0 = BT + (size_t)(n0 + srow) * K + scol;
  const int dstB = (srow) * 32 + (lane & 3) * 8;   // linear dest

  // A reg-staging: row arow, writes granules {2(lane&1), 2(lane&1)+1} ^ sw
  const int arow = w * 32 + (lane >> 1);
  const int acol = (lane & 1) * 16;
  const int sw = (lane >> 2) & 3;                  // (arow>>1)&3
  const int ag0 = (2 * (lane & 1)) ^ sw;
  const int ag1 = (2 * (lane & 1) + 1) ^ sw;
  const float* gA0f = Ain + (size_t)(m0 + arow) * K + acol;

  const int wr = w >> 1, wc = w & 1;
  const int g4 = lane >> 4, l16 = lane & 15;
  const int rsw = (l16 >> 1) & 3;
  const int aoff = (wr * 64 + l16) * 32 + 8 * (g4 ^ rsw);
  const int boff = (wc * 64 + l16) * 32 + 8 * (g4 ^ rsw);

  f32x4 acc[4][4] = {};
  float4 fA0, fA1, fA2, fA3;

  auto issueA = [&](int kt) {
    const float4* p = (const float4*)(gA0f + kt * 32);
    fA0 = p[0]; fA1 = p[1]; fA2 = p[2]; fA3 = p[3];
  };
  auto writeA = [&](int buf) {
    unsigned d0 = cvt_pk_bf16(fA0.x, fA0.y), d1 = cvt_pk_bf16(fA0.z, fA0.w);
    unsigned d2 = cvt_pk_bf16(fA1.x, fA1.y), d3 = cvt_pk_bf16(fA1.z, fA1.w);
    unsigned d4 = cvt_pk_bf16(fA2.x, fA2.y), d5 = cvt_pk_bf16(fA2.z, fA2.w);
    unsigned d6 = cvt_pk_bf16(fA3.x, fA3.y), d7 = cvt_pk_bf16(fA3.z, fA3.w);
    ushort* base = &sA[buf][arow * 32];
    uintx4 q0 = {d0, d1, d2, d3}, q1 = {d4, d5, d6, d7};
    *(uintx4*)(base + ag0 * 8) = q0;
    *(uintx4*)(base + ag1 * 8) = q1;
  };

  issueA(0);
  GLOAD_LDS16(gB0,          &sB[0][dstB]);
  GLOAD_LDS16(gB0 + 16 * K, &sB[0][dstB + 16 * 32]);
  writeA(0);

  for (int kt = 0; kt < NK; ++kt) {
    __syncthreads();
    const int nb = (kt + 1) & 1;
    if (kt + 1 < NK) {
      const ushort* gb = gB0 + (kt + 1) * 32;
      GLOAD_LDS16(gb,          &sB[nb][dstB]);
      GLOAD_LDS16(gb + 16 * K, &sB[nb][dstB + 16 * 32]);
      issueA(kt + 1);
    }
    const ushort* pa = &sA[kt & 1][aoff];
    const ushort* pb = &sB[kt & 1][boff];
    short8 af[4], bf[4];
#pragma unroll
    for (int i = 0; i < 4; ++i) {
      af[i] = *(const short8*)(pa + i * 16 * 32);
      bf[i] = *(const short8*)(pb + i * 16 * 32);
    }
#pragma unroll
    for (int mi = 0; mi < 4; ++mi)
#pragma unroll
      for (int ni = 0; ni < 4; ++ni)
        acc[mi][ni] = __builtin_amdgcn_mfma_f32_16x16x32_bf16(af[mi], bf[ni], acc[mi][ni], 0, 0, 0);
    if (kt + 1 < NK) writeA(nb);
  }

#pragma unroll
  for (int mi = 0; mi < 4; ++mi) {
#pragma unroll
    for (int ni = 0; ni < 4; ++ni) {
#pragma unroll
      for (int r = 0; r < 4; ++r) {
        int m = m0 + wr * 64 + mi * 16 + g4 * 4 + r;
        int n = n0 + wc * 64 + ni * 16 + l16;
        float vv = acc[mi][ni][r];
        int b = m / S_, pos = m % S_;
        if (EPI == 0) {
          int dd = n & 63;
          if (SWZ) dd ^= (pos & 7) << 3;      // K-LDS row bank swizzle
          ushort hv = f2bf(vv * oscale);
          ((ushort*)Cout)[(((size_t)b * HN + (n >> 6)) * SP + pos) * 64 + dd] = hv;
        } else {
          int local = pos & 31;
          int j = (local < 16) ? (2 * local) : (2 * local - 31);
          int pf_ = (pos & ~31) | (j ^ ((n & 3) << 3));   // sigma + granule bank swizzle
          ushort hv = f2bf(vv);
          ((ushort*)Cout)[(((size_t)b * HN + (n >> 6)) * 64 + (n & 63)) * SP + pf_] = hv;
        }
      }
    }
  }
}

// ---------------- fused GQA attention: LDS-staged K/V, packed P path ----------------
__global__ __launch_bounds__(256)
void attn_kernel(const ushort* __restrict__ qp, const ushort* __restrict__ kp,
                 const ushort* __restrict__ vpT, const float* __restrict__ rel,
                 ushort* __restrict__ ao) {
  __shared__ float sBias[1056];                   // +32 guard offset
  __shared__ alignas(16) ushort sK[2][32 * 64];
  __shared__ alignas(16) ushort sV[2][64 * 32];
  __shared__ alignas(16) ushort sP[4][16 * 40];
  const int tid = threadIdx.x;
  const int blk = blockIdx.x;
  const int logical = (blk & 7) * 512 + (blk >> 3);     // bijective (4096 = 8*512)
  const int qt = logical & 7, head = (logical >> 3) & 15, b = logical >> 7;
  const int g = head >> 2;
  const float LOG2E = 1.44269504f;
  for (int t = tid; t < 1056; t += 256)
    sBias[t] = (t >= 32 && t < 999) ? rel[(t - 32) * 16 + head] * LOG2E : -1e30f;

  const int lane = tid & 63, w = tid >> 6;
  const int g4 = lane >> 4, l16 = lane & 15;
  const int qw = qt * 64 + w * 16;

  const ushort* qbase = qp + (((size_t)b * NH + head) * SP + qw + l16) * 64;
  short8 qf0 = *(const short8*)(qbase + 8 * g4);
  short8 qf1 = *(const short8*)(qbase + 32 + 8 * g4);

  const ushort* kSrc = kp  + ((size_t)b * 4 + g) * SP * 64 + (tid >> 3) * 64 + (tid & 7) * 8;
  const ushort* vSrc = vpT + ((size_t)b * 4 + g) * 64 * SP + (tid >> 2) * SP + (tid & 3) * 8;

  f32x4 acc[4] = {};
  float ps[4] = {0.f, 0.f, 0.f, 0.f};
  const int ib = l16 - (qw + g4 * 4) + 483 + 32;
  ushort* sPw = &sP[w][0];

  const int kswz  = (l16 & 7) << 3;
  const int kOff0 = l16 * 64 + ((8 * g4) ^ kswz);
  const int kOff1 = l16 * 64 + ((32 + 8 * g4) ^ kswz);
  const int vOff  = l16 * 32 + 8 * (g4 ^ (l16 & 3));

  GLOAD_LDS16(kSrc, &sK[0][w * 512]);
  GLOAD_LDS16(vSrc, &sV[0][w * 512]);

  for (int kt = 0; kt < 16; ++kt) {
    __syncthreads();
    if (kt + 1 < 16) {
      GLOAD_LDS16(kSrc + (kt + 1) * 2048, &sK[(kt + 1) & 1][w * 512]);
      GLOAD_LDS16(vSrc + (kt + 1) * 32,   &sV[(kt + 1) & 1][w * 512]);
    }
    const ushort* sk = &sK[kt & 1][0];
    const ushort* sv = &sV[kt & 1][0];
    short8 kf0 = *(const short8*)(sk + kOff0);
    short8 kf1 = *(const short8*)(sk + kOff1);
    short8 kf2 = *(const short8*)(sk + 1024 + kOff0);
    short8 kf3 = *(const short8*)(sk + 1024 + kOff1);
    f32x4 s0 = {}, s1 = {};
    s0 = __builtin_amdgcn_mfma_f32_16x16x32_bf16(qf0, kf0, s0, 0, 0, 0);
    s0 = __builtin_amdgcn_mfma_f32_16x16x32_bf16(qf1, kf1, s0, 0, 0, 0);
    s1 = __builtin_amdgcn_mfma_f32_16x16x32_bf16(qf0, kf2, s1, 0, 0, 0);
    s1 = __builtin_amdgcn_mfma_f32_16x16x32_bf16(qf1, kf3, s1, 0, 0, 0);

    const int k0 = kt * 32;
#pragma unroll
    for (int r = 0; r < 4; ++r) {
      int i0 = ib + k0 - r;
      float p0 = __builtin_amdgcn_exp2f(s0[r] + sBias[i0]);
      float p1 = __builtin_amdgcn_exp2f(s1[r] + sBias[i0 + 16]);
      if (kt == 15) {                       // mask BEFORE store: pad P == 0 exactly
        p0 = (k0 + l16 < S_) ? p0 : 0.f;
        p1 = (k0 + 16 + l16 < S_) ? p1 : 0.f;
      }
      ps[r] += p0 + p1;
      *(unsigned*)(sPw + (g4 * 4 + r) * 40 + 2 * l16) = cvt_pk_bf16(p0, p1);
    }
    short8 pf = *(const short8*)(sPw + l16 * 40 + 8 * g4);
#pragma unroll
    for (int nt = 0; nt < 4; ++nt) {
      short8 vf = *(const short8*)(sv + vOff + nt * 512);
      acc[nt] = __builtin_amdgcn_mfma_f32_16x16x32_bf16(pf, vf, acc[nt], 0, 0, 0);
    }
  }

#pragma unroll
  for (int off = 1; off < 16; off <<= 1) {
#pragma unroll
    for (int r = 0; r < 4; ++r) ps[r] += __shfl_xor(ps[r], off, 64);
  }

#pragma unroll
  for (int r = 0; r < 4; ++r) {
    int q_abs = qw + g4 * 4 + r;
    if (q_abs < S_) {
      float inv = 1.f / ps[r];
#pragma unroll
      for (int nt = 0; nt < 4; ++nt) {
        int dd = nt * 16 + l16;
        ao[((size_t)b * S_ + q_abs) * 1024 + head * 64 + dd] = f2bf(acc[nt][r] * inv);
      }
    }
  }
}

extern "C" void kernel_launch(void* const* d_in, const int* in_sizes, int n_in,
                              void* d_out, int out_size, void* d_ws, size_t ws_size,
                              hipStream_t stream) {
  const float* query = (const float*)d_in[0];
  const float* key   = (const float*)d_in[1];
  const float* value = (const float*)d_in[2];
  const float* Wq    = (const float*)d_in[3];
  const float* Wk    = (const float*)d_in[4];
  const float* Wv    = (const float*)d_in[5];
  const float* Wo    = (const float*)d_in[6];
  const float* rel   = (const float*)d_in[7];

  char* ws = (char*)d_ws;
  size_t off = 0;
  auto alloc = [&](size_t bytes) { char* p = ws + off; off += (bytes + 255) & ~(size_t)255; return p; };

  const size_t MEelems = (size_t)M_ * E_;             // 15,859,712
  ushort* qb  = (ushort*)alloc(MEelems * 2);          // query in bf16
  ushort* wqT = (ushort*)alloc((size_t)1024 * 1024 * 2);
  ushort* wkT = (ushort*)alloc((size_t)256 * 1024 * 2);
  ushort* wvT = (ushort*)alloc((size_t)256 * 1024 * 2);
  ushort* woT = (ushort*)alloc((size_t)1024 * 1024 * 2);
  ushort* qp  = (ushort*)alloc((size_t)B_ * NH * SP * 64 * 2);   // 32 MB
  ushort* kp  = (ushort*)alloc((size_t)B_ * 4 * SP * 64 * 2);    // 8 MB
  ushort* vp  = (ushort*)alloc((size_t)B_ * 4 * 64 * SP * 2);    // 8 MB
  ushort* ao  = (ushort*)alloc(MEelems * 2);

  cvt_f32_bf16<<<2048, 256, 0, stream>>>(query, qb, (int)(MEelems / 4));

  transpose_convert<<<dim3(32, 32), dim3(32, 8), 0, stream>>>(Wq, wqT, 1024, 1024);
  transpose_convert<<<dim3(8, 32),  dim3(32, 8), 0, stream>>>(Wk, wkT, 1024, 256);
  transpose_convert<<<dim3(8, 32),  dim3(32, 8), 0, stream>>>(Wv, wvT, 1024, 256);
  transpose_convert<<<dim3(32, 32), dim3(32, 8), 0, stream>>>(Wo, woT, 1024, 1024);

  const float QSCALE = 0.125f * 1.44269504f;   // fold 1/sqrt(D) and log2e into q
  gemm_cnt256<0><<<244, 512, 0, stream>>>(qb, wqT, qp, QSCALE);
  gemm_bt<0,1,1><<<242, 256, 0, stream>>>(key,   wkT, kp, 256, 1024, 4, 1.0f);
  gemm_bt<1,1,1><<<242, 256, 0, stream>>>(value, wvT, vp, 256, 1024, 4, 1.0f);

  attn_kernel<<<4096, 256, 0, stream>>>(qp, kp, vp, rel, ao);

  gemm_cnt256<2><<<244, 512, 0, stream>>>(ao, woT, d_out, 1.0f);
}

// Round 11
// 258.444 us; speedup vs baseline: 1.1552x; 1.1499x over previous
//
#include <hip/hip_runtime.h>
#include <hip/hip_bf16.h>

typedef __attribute__((ext_vector_type(8))) short short8;
typedef __attribute__((ext_vector_type(4))) float f32x4;
typedef __attribute__((ext_vector_type(4))) unsigned uintx4;

#define B_  32
#define S_  484
#define E_  1024
#define NH  16
#define SP  512          // padded sequence length
#define M_  (B_*S_)      // 15488

static __device__ __forceinline__ ushort f2bf(float f) {
  union { float f; unsigned u; } v; v.f = f;
  unsigned u = v.u;
  return (ushort)((u + 0x7FFFu + ((u >> 16) & 1u)) >> 16);
}

static __device__ __forceinline__ unsigned cvt_pk_bf16(float lo, float hi) {
  unsigned r;
  asm("v_cvt_pk_bf16_f32 %0, %1, %2" : "=v"(r) : "v"(lo), "v"(hi));
  return r;
}

#define GLOAD_LDS16(gp, lp) \
  __builtin_amdgcn_global_load_lds((const __attribute__((address_space(1))) void*)(gp), \
                                   (__attribute__((address_space(3))) void*)(lp), 16, 0, 0)

// ---------------- f32 -> bf16 flat convert ----------------
__global__ __launch_bounds__(256)
void cvt_f32_bf16(const float* __restrict__ x, ushort* __restrict__ y, int n4) {
  int i = blockIdx.x * 256 + threadIdx.x;
  int stride = gridDim.x * 256;
  for (; i < n4; i += stride) {
    float4 v = ((const float4*)x)[i];
    ushort4 h;
    h.x = f2bf(v.x); h.y = f2bf(v.y); h.z = f2bf(v.z); h.w = f2bf(v.w);
    ((ushort4*)y)[i] = h;
  }
}

// ---------------- all 4 weight transposes in one launch ----------------
__global__ __launch_bounds__(256)
void transpose_all(const float* __restrict__ Wq, const float* __restrict__ Wk,
                   const float* __restrict__ Wv, const float* __restrict__ Wo,
                   ushort* __restrict__ wqT, ushort* __restrict__ wkT,
                   ushort* __restrict__ wvT, ushort* __restrict__ woT) {
  __shared__ float tile[32][33];
  int t = blockIdx.x;
  const float* W; ushort* WT; int N;
  if (t < 1024)      { W = Wq; WT = wqT; N = 1024; }
  else if (t < 1280) { W = Wk; WT = wkT; N = 256;  t -= 1024; }
  else if (t < 1536) { W = Wv; WT = wvT; N = 256;  t -= 1280; }
  else               { W = Wo; WT = woT; N = 1024; t -= 1536; }
  const int nx = N >> 5;
  const int n0 = (t % nx) * 32, k0 = (t / nx) * 32;
  const int tx = threadIdx.x & 31, ty = threadIdx.x >> 5;   // 32 x 8
  for (int i = ty; i < 32; i += 8) tile[i][tx] = W[(size_t)(k0 + i) * N + n0 + tx];
  __syncthreads();
  for (int i = ty; i < 32; i += 8) WT[(size_t)(n0 + i) * 1024 + k0 + tx] = f2bf(tile[tx][i]);
}

// ======== counted-vmcnt GEMM: 256x256 tile, 512 thr, 4-buffer depth-3 ========
// T4: steady-state vmcnt(8) keeps 2 full tile-stages in flight across barriers.
// XCD-chunked 1D grid (244). M tail: clamp-load + guard-store.
// EPI 0: bf16 out (scaled), ((b*NH+h)*SP + pos)*64 + (n&63)    (qp)
// EPI 2: f32 out, row-major [M][1024]                          (d_out)
template<int EPI>
__global__ __launch_bounds__(512)
void gemm_cnt256(const ushort* __restrict__ A, const ushort* __restrict__ BT,
                 void* __restrict__ Cout, float oscale) {
  const int K = 1024, N = 1024, NK = 32;
  __shared__ alignas(16) ushort sA[4][256 * 32];
  __shared__ alignas(16) ushort sB[4][256 * 32];
  const int tid = threadIdx.x;
  const int lane = tid & 63, w = tid >> 6;        // 8 waves

  const int nwg = gridDim.x;
  const int qq = nwg >> 3, rr = nwg & 7;
  const int x = blockIdx.x & 7, seq = blockIdx.x >> 3;
  const int logical = x * qq + (x < rr ? x : rr) + seq;
  const int m0 = (logical >> 2) * 256;            // 61 m-tiles
  const int n0 = (logical & 3) * 256;             // 4 n-tiles

  // staging: 4 threads/row; source col pre-swizzled (T2, rule #21)
  const int brow = tid >> 2;
  const int scol = (((tid & 3) ^ ((tid >> 3) & 3))) * 8;
  const int rowA0 = min(m0 + brow, M_ - 1);
  const int rowA1 = min(m0 + brow + 128, M_ - 1);
  const ushort* gA0 = A + (size_t)rowA0 * K + scol;
  const ushort* gA1 = A + (size_t)rowA1 * K + scol;
  const ushort* gB0 = BT + (size_t)(n0 + brow) * K + scol;
  const int dst = tid * 8;

  const int wr = w >> 2, wc = w & 3;              // 2x4 wave grid, each 128x64
  const int g4 = lane >> 4, l16 = lane & 15;
  const int rs = (l16 >> 1) & 3;                  // folded read-swizzle term

  f32x4 acc[8][4] = {};

  auto stage = [&](int kt, int buf) {             // 4 vmem ops/thread
    GLOAD_LDS16(gA0 + kt * 32,           &sA[buf][dst]);
    GLOAD_LDS16(gA1 + kt * 32,           &sA[buf][dst + 4096]);
    GLOAD_LDS16(gB0 + kt * 32,           &sB[buf][dst]);
    GLOAD_LDS16(gB0 + kt * 32 + 128 * K, &sB[buf][dst + 4096]);
  };

  stage(0, 0);
  stage(1, 1);
  stage(2, 2);

  int cur = 0;
  for (int kt = 0; kt < NK; ++kt) {
    // wait tile kt only; stages kt+1,kt+2 stay in flight across the barrier
    if (kt < NK - 2)       asm volatile("s_waitcnt vmcnt(8)" ::: "memory");
    else if (kt == NK - 2) asm volatile("s_waitcnt vmcnt(4)" ::: "memory");
    else                   asm volatile("s_waitcnt vmcnt(0)" ::: "memory");
    asm volatile("s_waitcnt lgkmcnt(0)" ::: "memory");
    __builtin_amdgcn_s_barrier();
    if (kt + 3 < NK) stage(kt + 3, (cur + 3) & 3);
    const ushort* pa = &sA[cur][(wr * 128 + l16) * 32 + 8 * (g4 ^ rs)];
    const ushort* pb = &sB[cur][(wc * 64 + l16) * 32 + 8 * (g4 ^ rs)];
    short8 af[8], bf[4];
#pragma unroll
    for (int i = 0; i < 8; ++i) af[i] = *(const short8*)(pa + i * 16 * 32);
#pragma unroll
    for (int i = 0; i < 4; ++i) bf[i] = *(const short8*)(pb + i * 16 * 32);
#pragma unroll
    for (int mi = 0; mi < 8; ++mi)
#pragma unroll
      for (int ni = 0; ni < 4; ++ni)
        acc[mi][ni] = __builtin_amdgcn_mfma_f32_16x16x32_bf16(af[mi], bf[ni], acc[mi][ni], 0, 0, 0);
    cur = (cur + 1) & 3;
  }

#pragma unroll
  for (int mi = 0; mi < 8; ++mi) {
#pragma unroll
    for (int ni = 0; ni < 4; ++ni) {
#pragma unroll
      for (int r = 0; r < 4; ++r) {
        int m = m0 + wr * 128 + mi * 16 + g4 * 4 + r;
        int n = n0 + wc * 64 + ni * 16 + l16;
        if (m < M_) {
          float vv = acc[mi][ni][r];
          if (EPI == 2) {
            ((float*)Cout)[(size_t)m * N + n] = vv;
          } else {
            int b = m / S_, pos = m % S_;
            ushort hv = f2bf(vv * oscale);
            ((ushort*)Cout)[(((size_t)b * NH + (n >> 6)) * SP + pos) * 64 + (n & 63)] = hv;
          }
        }
      }
    }
  }
}

// ---------------- fused K+V projection GEMMs (128x128, f32 A reg-staged) ----------------
// logical < 242: K-proj (A=key, B=wkT, out=kp, d^=(pos&7)<<3 swizzle)
// logical >= 242: V-proj (A=value, B=wvT, out=vp, sigma permute + granule xor)
__global__ __launch_bounds__(256)
void kvproj(const float* __restrict__ key, const float* __restrict__ value,
            const ushort* __restrict__ wkT, const ushort* __restrict__ wvT,
            ushort* __restrict__ kp, ushort* __restrict__ vp) {
  const int K = 1024, NK = 32;
  __shared__ alignas(16) ushort sA[2][128 * 32];
  __shared__ alignas(16) ushort sB[2][128 * 32];
  const int tid = threadIdx.x;
  const int lane = tid & 63, w = tid >> 6;

  const int nwg = gridDim.x;                       // 484
  const int qq = nwg >> 3, rr = nwg & 7;
  const int x = blockIdx.x & 7, seq = blockIdx.x >> 3;
  const int logical = x * qq + (x < rr ? x : rr) + seq;
  const bool isV = logical >= 242;
  const int l2 = isV ? logical - 242 : logical;
  const int m0 = (l2 >> 1) * 128;
  const int n0 = (l2 & 1) * 128;
  const float* Ain = isV ? value : key;
  const ushort* BT = isV ? wvT : wkT;
  ushort* Cout = isV ? vp : kp;

  const int srow = w * 32 + (lane >> 2);
  const int scol = ((lane & 3) ^ ((lane >> 3) & 3)) * 8;
  const ushort* gB0 = BT + (size_t)(n0 + srow) * K + scol;
  const int dstB = srow * 32 + (lane & 3) * 8;

  const int arow = w * 32 + (lane >> 1);
  const int acol = (lane & 1) * 16;
  const int sw = (lane >> 2) & 3;
  const int ag0 = (2 * (lane & 1)) ^ sw;
  const int ag1 = (2 * (lane & 1) + 1) ^ sw;
  const float* gA0f = Ain + (size_t)(m0 + arow) * K + acol;

  const int wr = w >> 1, wc = w & 1;
  const int g4 = lane >> 4, l16 = lane & 15;
  const int rsw = (l16 >> 1) & 3;
  const int aoff = (wr * 64 + l16) * 32 + 8 * (g4 ^ rsw);
  const int boff = (wc * 64 + l16) * 32 + 8 * (g4 ^ rsw);

  f32x4 acc[4][4] = {};
  float4 fA0, fA1, fA2, fA3;

  auto issueA = [&](int kt) {
    const float4* p = (const float4*)(gA0f + kt * 32);
    fA0 = p[0]; fA1 = p[1]; fA2 = p[2]; fA3 = p[3];
  };
  auto writeA = [&](int buf) {
    unsigned d0 = cvt_pk_bf16(fA0.x, fA0.y), d1 = cvt_pk_bf16(fA0.z, fA0.w);
    unsigned d2 = cvt_pk_bf16(fA1.x, fA1.y), d3 = cvt_pk_bf16(fA1.z, fA1.w);
    unsigned d4 = cvt_pk_bf16(fA2.x, fA2.y), d5 = cvt_pk_bf16(fA2.z, fA2.w);
    unsigned d6 = cvt_pk_bf16(fA3.x, fA3.y), d7 = cvt_pk_bf16(fA3.z, fA3.w);
    ushort* base = &sA[buf][arow * 32];
    uintx4 q0 = {d0, d1, d2, d3}, q1 = {d4, d5, d6, d7};
    *(uintx4*)(base + ag0 * 8) = q0;
    *(uintx4*)(base + ag1 * 8) = q1;
  };

  issueA(0);
  GLOAD_LDS16(gB0,          &sB[0][dstB]);
  GLOAD_LDS16(gB0 + 16 * K, &sB[0][dstB + 16 * 32]);
  writeA(0);

  for (int kt = 0; kt < NK; ++kt) {
    __syncthreads();
    const int nb = (kt + 1) & 1;
    if (kt + 1 < NK) {
      const ushort* gb = gB0 + (kt + 1) * 32;
      GLOAD_LDS16(gb,          &sB[nb][dstB]);
      GLOAD_LDS16(gb + 16 * K, &sB[nb][dstB + 16 * 32]);
      issueA(kt + 1);
    }
    const ushort* pa = &sA[kt & 1][aoff];
    const ushort* pb = &sB[kt & 1][boff];
    short8 af[4], bf[4];
#pragma unroll
    for (int i = 0; i < 4; ++i) {
      af[i] = *(const short8*)(pa + i * 16 * 32);
      bf[i] = *(const short8*)(pb + i * 16 * 32);
    }
#pragma unroll
    for (int mi = 0; mi < 4; ++mi)
#pragma unroll
      for (int ni = 0; ni < 4; ++ni)
        acc[mi][ni] = __builtin_amdgcn_mfma_f32_16x16x32_bf16(af[mi], bf[ni], acc[mi][ni], 0, 0, 0);
    if (kt + 1 < NK) writeA(nb);
  }

#pragma unroll
  for (int mi = 0; mi < 4; ++mi) {
#pragma unroll
    for (int ni = 0; ni < 4; ++ni) {
#pragma unroll
      for (int r = 0; r < 4; ++r) {
        int m = m0 + wr * 64 + mi * 16 + g4 * 4 + r;
        int n = n0 + wc * 64 + ni * 16 + l16;
        float vv = acc[mi][ni][r];
        int b = m / S_, pos = m % S_;
        if (!isV) {
          int dd = (n & 63) ^ ((pos & 7) << 3);
          Cout[(((size_t)b * 4 + (n >> 6)) * SP + pos) * 64 + dd] = f2bf(vv);
        } else {
          int local = pos & 31;
          int j = (local < 16) ? (2 * local) : (2 * local - 31);
          int pf_ = (pos & ~31) | (j ^ ((n & 3) << 3));
          Cout[(((size_t)b * 4 + (n >> 6)) * 64 + (n & 63)) * SP + pf_] = f2bf(vv);
        }
      }
    }
  }
}

// ---------------- fused GQA attention: LDS-staged K/V, paired-bias C-init ----------------
__global__ __launch_bounds__(256)
void attn_kernel(const ushort* __restrict__ qp, const ushort* __restrict__ kp,
                 const ushort* __restrict__ vpT, const float* __restrict__ rel,
                 ushort* __restrict__ ao) {
  __shared__ float2 sBiasP[1056];                 // (b[i], b[i+16]) pairs, +32 guard
  __shared__ alignas(16) ushort sK[2][32 * 64];
  __shared__ alignas(16) ushort sV[2][64 * 32];
  __shared__ alignas(16) ushort sP[4][16 * 40];
  const int tid = threadIdx.x;
  const int blk = blockIdx.x;
  const int logical = (blk & 7) * 512 + (blk >> 3);     // bijective (4096 = 8*512)
  const int qt = logical & 7, head = (logical >> 3) & 15, b = logical >> 7;
  const int g = head >> 2;
  const float LOG2E = 1.44269504f;
  for (int t = tid; t < 1056; t += 256) {
    float b0 = (t >= 32 && t < 999) ? rel[(t - 32) * 16 + head] * LOG2E : -1e30f;
    int t2 = t + 16;
    float b1 = (t2 >= 32 && t2 < 999) ? rel[(t2 - 32) * 16 + head] * LOG2E : -1e30f;
    sBiasP[t] = make_float2(b0, b1);
  }

  const int lane = tid & 63, w = tid >> 6;
  const int g4 = lane >> 4, l16 = lane & 15;
  const int qw = qt * 64 + w * 16;

  const ushort* qbase = qp + (((size_t)b * NH + head) * SP + qw + l16) * 64;
  short8 qf0 = *(const short8*)(qbase + 8 * g4);
  short8 qf1 = *(const short8*)(qbase + 32 + 8 * g4);

  const ushort* kSrc = kp  + ((size_t)b * 4 + g) * SP * 64 + (tid >> 3) * 64 + (tid & 7) * 8;
  const ushort* vSrc = vpT + ((size_t)b * 4 + g) * 64 * SP + (tid >> 2) * SP + (tid & 3) * 8;

  f32x4 acc[4] = {};
  float ps[4] = {0.f, 0.f, 0.f, 0.f};
  const int ib = l16 - (qw + g4 * 4) + 483 + 32;   // pair-table idx (guarded)
  ushort* sPw = &sP[w][0];

  const int kswz  = (l16 & 7) << 3;
  const int kOff0 = l16 * 64 + ((8 * g4) ^ kswz);
  const int kOff1 = l16 * 64 + ((32 + 8 * g4) ^ kswz);
  const int vOff  = l16 * 32 + 8 * (g4 ^ (l16 & 3));

  GLOAD_LDS16(kSrc, &sK[0][w * 512]);
  GLOAD_LDS16(vSrc, &sV[0][w * 512]);

  for (int kt = 0; kt < 16; ++kt) {
    __syncthreads();
    if (kt + 1 < 16) {
      GLOAD_LDS16(kSrc + (kt + 1) * 2048, &sK[(kt + 1) & 1][w * 512]);
      GLOAD_LDS16(vSrc + (kt + 1) * 32,   &sV[(kt + 1) & 1][w * 512]);
    }
    const int k0 = kt * 32;
    // paired bias reads (4 x ds_read_b64) -> MFMA C-init (bias added by matrix pipe)
    float2 bb0 = sBiasP[ib + k0];
    float2 bb1 = sBiasP[ib + k0 - 1];
    float2 bb2 = sBiasP[ib + k0 - 2];
    float2 bb3 = sBiasP[ib + k0 - 3];
    f32x4 s0 = {bb0.x, bb1.x, bb2.x, bb3.x};
    f32x4 s1 = {bb0.y, bb1.y, bb2.y, bb3.y};

    const ushort* sk = &sK[kt & 1][0];
    const ushort* sv = &sV[kt & 1][0];
    short8 kf0 = *(const short8*)(sk + kOff0);
    short8 kf1 = *(const short8*)(sk + kOff1);
    short8 kf2 = *(const short8*)(sk + 1024 + kOff0);
    short8 kf3 = *(const short8*)(sk + 1024 + kOff1);
    __builtin_amdgcn_s_setprio(1);
    s0 = __builtin_amdgcn_mfma_f32_16x16x32_bf16(qf0, kf0, s0, 0, 0, 0);
    s0 = __builtin_amdgcn_mfma_f32_16x16x32_bf16(qf1, kf1, s0, 0, 0, 0);
    s1 = __builtin_amdgcn_mfma_f32_16x16x32_bf16(qf0, kf2, s1, 0, 0, 0);
    s1 = __builtin_amdgcn_mfma_f32_16x16x32_bf16(qf1, kf3, s1, 0, 0, 0);
    __builtin_amdgcn_s_setprio(0);

#pragma unroll
    for (int r = 0; r < 4; ++r) {
      float p0 = __builtin_amdgcn_exp2f(s0[r]);
      float p1 = __builtin_amdgcn_exp2f(s1[r]);
      if (kt == 15) {                       // mask BEFORE store: pad P == 0 exactly
        p0 = (k0 + l16 < S_) ? p0 : 0.f;
        p1 = (k0 + 16 + l16 < S_) ? p1 : 0.f;
      }
      ps[r] += p0 + p1;
      *(unsigned*)(sPw + (g4 * 4 + r) * 40 + 2 * l16) = cvt_pk_bf16(p0, p1);
    }
    short8 pf = *(const short8*)(sPw + l16 * 40 + 8 * g4);
    __builtin_amdgcn_s_setprio(1);
#pragma unroll
    for (int nt = 0; nt < 4; ++nt) {
      short8 vf = *(const short8*)(sv + vOff + nt * 512);
      acc[nt] = __builtin_amdgcn_mfma_f32_16x16x32_bf16(pf, vf, acc[nt], 0, 0, 0);
    }
    __builtin_amdgcn_s_setprio(0);
  }

#pragma unroll
  for (int off = 1; off < 16; off <<= 1) {
#pragma unroll
    for (int r = 0; r < 4; ++r) ps[r] += __shfl_xor(ps[r], off, 64);
  }

#pragma unroll
  for (int r = 0; r < 4; ++r) {
    int q_abs = qw + g4 * 4 + r;
    if (q_abs < S_) {
      float inv = 1.f / ps[r];
#pragma unroll
      for (int nt = 0; nt < 4; ++nt) {
        int dd = nt * 16 + l16;
        ao[((size_t)b * S_ + q_abs) * 1024 + head * 64 + dd] = f2bf(acc[nt][r] * inv);
      }
    }
  }
}

extern "C" void kernel_launch(void* const* d_in, const int* in_sizes, int n_in,
                              void* d_out, int out_size, void* d_ws, size_t ws_size,
                              hipStream_t stream) {
  const float* query = (const float*)d_in[0];
  const float* key   = (const float*)d_in[1];
  const float* value = (const float*)d_in[2];
  const float* Wq    = (const float*)d_in[3];
  const float* Wk    = (const float*)d_in[4];
  const float* Wv    = (const float*)d_in[5];
  const float* Wo    = (const float*)d_in[6];
  const float* rel   = (const float*)d_in[7];

  char* ws = (char*)d_ws;
  size_t off = 0;
  auto alloc = [&](size_t bytes) { char* p = ws + off; off += (bytes + 255) & ~(size_t)255; return p; };

  const size_t MEelems = (size_t)M_ * E_;             // 15,859,712
  ushort* qb  = (ushort*)alloc(MEelems * 2);          // query in bf16
  ushort* wqT = (ushort*)alloc((size_t)1024 * 1024 * 2);
  ushort* wkT = (ushort*)alloc((size_t)256 * 1024 * 2);
  ushort* wvT = (ushort*)alloc((size_t)256 * 1024 * 2);
  ushort* woT = (ushort*)alloc((size_t)1024 * 1024 * 2);
  ushort* qp  = (ushort*)alloc((size_t)B_ * NH * SP * 64 * 2);   // 32 MB
  ushort* kp  = (ushort*)alloc((size_t)B_ * 4 * SP * 64 * 2);    // 8 MB
  ushort* vp  = (ushort*)alloc((size_t)B_ * 4 * 64 * SP * 2);    // 8 MB
  ushort* ao  = (ushort*)alloc(MEelems * 2);

  cvt_f32_bf16<<<2048, 256, 0, stream>>>(query, qb, (int)(MEelems / 4));

  transpose_all<<<2560, 256, 0, stream>>>(Wq, Wk, Wv, Wo, wqT, wkT, wvT, woT);

  const float QSCALE = 0.125f * 1.44269504f;   // fold 1/sqrt(D) and log2e into q
  gemm_cnt256<0><<<244, 512, 0, stream>>>(qb, wqT, qp, QSCALE);
  kvproj<<<484, 256, 0, stream>>>(key, value, wkT, wvT, kp, vp);

  attn_kernel<<<4096, 256, 0, stream>>>(qp, kp, vp, rel, ao);

  gemm_cnt256<2><<<244, 512, 0, stream>>>(ao, woT, d_out, 1.0f);
}

// Round 12
// 256.366 us; speedup vs baseline: 1.1645x; 1.0081x over previous
//
#include <hip/hip_runtime.h>
#include <hip/hip_bf16.h>

typedef __attribute__((ext_vector_type(8))) short short8;
typedef __attribute__((ext_vector_type(4))) float f32x4;
typedef __attribute__((ext_vector_type(4))) unsigned uintx4;

#define B_  32
#define S_  484
#define E_  1024
#define NH  16
#define SP  512          // padded sequence length
#define M_  (B_*S_)      // 15488

static __device__ __forceinline__ ushort f2bf(float f) {
  union { float f; unsigned u; } v; v.f = f;
  unsigned u = v.u;
  return (ushort)((u + 0x7FFFu + ((u >> 16) & 1u)) >> 16);
}

static __device__ __forceinline__ unsigned cvt_pk_bf16(float lo, float hi) {
  unsigned r;
  asm("v_cvt_pk_bf16_f32 %0, %1, %2" : "=v"(r) : "v"(lo), "v"(hi));
  return r;
}

#define GLOAD_LDS16(gp, lp) \
  __builtin_amdgcn_global_load_lds((const __attribute__((address_space(1))) void*)(gp), \
                                   (__attribute__((address_space(3))) void*)(lp), 16, 0, 0)

// ---------------- f32 -> bf16 flat convert ----------------
__global__ __launch_bounds__(256)
void cvt_f32_bf16(const float* __restrict__ x, ushort* __restrict__ y, int n4) {
  int i = blockIdx.x * 256 + threadIdx.x;
  int stride = gridDim.x * 256;
  for (; i < n4; i += stride) {
    float4 v = ((const float4*)x)[i];
    ushort4 h;
    h.x = f2bf(v.x); h.y = f2bf(v.y); h.z = f2bf(v.z); h.w = f2bf(v.w);
    ((ushort4*)y)[i] = h;
  }
}

// ---------------- all 4 weight transposes in one launch ----------------
__global__ __launch_bounds__(256)
void transpose_all(const float* __restrict__ Wq, const float* __restrict__ Wk,
                   const float* __restrict__ Wv, const float* __restrict__ Wo,
                   ushort* __restrict__ wqT, ushort* __restrict__ wkT,
                   ushort* __restrict__ wvT, ushort* __restrict__ woT) {
  __shared__ float tile[32][33];
  int t = blockIdx.x;
  const float* W; ushort* WT; int N;
  if (t < 1024)      { W = Wq; WT = wqT; N = 1024; }
  else if (t < 1280) { W = Wk; WT = wkT; N = 256;  t -= 1024; }
  else if (t < 1536) { W = Wv; WT = wvT; N = 256;  t -= 1280; }
  else               { W = Wo; WT = woT; N = 1024; t -= 1536; }
  const int nx = N >> 5;
  const int n0 = (t % nx) * 32, k0 = (t / nx) * 32;
  const int tx = threadIdx.x & 31, ty = threadIdx.x >> 5;   // 32 x 8
  for (int i = ty; i < 32; i += 8) tile[i][tx] = W[(size_t)(k0 + i) * N + n0 + tx];
  __syncthreads();
  for (int i = ty; i < 32; i += 8) WT[(size_t)(n0 + i) * 1024 + k0 + tx] = f2bf(tile[tx][i]);
}

// ======== counted-vmcnt GEMM: 256x256 tile, 512 thr, 4-buffer depth-3 ========
template<int EPI>
__global__ __launch_bounds__(512)
void gemm_cnt256(const ushort* __restrict__ A, const ushort* __restrict__ BT,
                 void* __restrict__ Cout, float oscale) {
  const int K = 1024, N = 1024, NK = 32;
  __shared__ alignas(16) ushort sA[4][256 * 32];
  __shared__ alignas(16) ushort sB[4][256 * 32];
  const int tid = threadIdx.x;
  const int lane = tid & 63, w = tid >> 6;        // 8 waves

  const int nwg = gridDim.x;
  const int qq = nwg >> 3, rr = nwg & 7;
  const int x = blockIdx.x & 7, seq = blockIdx.x >> 3;
  const int logical = x * qq + (x < rr ? x : rr) + seq;
  const int m0 = (logical >> 2) * 256;            // 61 m-tiles
  const int n0 = (logical & 3) * 256;             // 4 n-tiles

  const int brow = tid >> 2;
  const int scol = (((tid & 3) ^ ((tid >> 3) & 3))) * 8;
  const int rowA0 = min(m0 + brow, M_ - 1);
  const int rowA1 = min(m0 + brow + 128, M_ - 1);
  const ushort* gA0 = A + (size_t)rowA0 * K + scol;
  const ushort* gA1 = A + (size_t)rowA1 * K + scol;
  const ushort* gB0 = BT + (size_t)(n0 + brow) * K + scol;
  const int dst = tid * 8;

  const int wr = w >> 2, wc = w & 3;              // 2x4 wave grid, each 128x64
  const int g4 = lane >> 4, l16 = lane & 15;
  const int rs = (l16 >> 1) & 3;

  f32x4 acc[8][4] = {};

  auto stage = [&](int kt, int buf) {
    GLOAD_LDS16(gA0 + kt * 32,           &sA[buf][dst]);
    GLOAD_LDS16(gA1 + kt * 32,           &sA[buf][dst + 4096]);
    GLOAD_LDS16(gB0 + kt * 32,           &sB[buf][dst]);
    GLOAD_LDS16(gB0 + kt * 32 + 128 * K, &sB[buf][dst + 4096]);
  };

  stage(0, 0);
  stage(1, 1);
  stage(2, 2);

  int cur = 0;
  for (int kt = 0; kt < NK; ++kt) {
    if (kt < NK - 2)       asm volatile("s_waitcnt vmcnt(8)" ::: "memory");
    else if (kt == NK - 2) asm volatile("s_waitcnt vmcnt(4)" ::: "memory");
    else                   asm volatile("s_waitcnt vmcnt(0)" ::: "memory");
    asm volatile("s_waitcnt lgkmcnt(0)" ::: "memory");
    __builtin_amdgcn_s_barrier();
    if (kt + 3 < NK) stage(kt + 3, (cur + 3) & 3);
    const ushort* pa = &sA[cur][(wr * 128 + l16) * 32 + 8 * (g4 ^ rs)];
    const ushort* pb = &sB[cur][(wc * 64 + l16) * 32 + 8 * (g4 ^ rs)];
    short8 af[8], bf[4];
#pragma unroll
    for (int i = 0; i < 8; ++i) af[i] = *(const short8*)(pa + i * 16 * 32);
#pragma unroll
    for (int i = 0; i < 4; ++i) bf[i] = *(const short8*)(pb + i * 16 * 32);
#pragma unroll
    for (int mi = 0; mi < 8; ++mi)
#pragma unroll
      for (int ni = 0; ni < 4; ++ni)
        acc[mi][ni] = __builtin_amdgcn_mfma_f32_16x16x32_bf16(af[mi], bf[ni], acc[mi][ni], 0, 0, 0);
    cur = (cur + 1) & 3;
  }

#pragma unroll
  for (int mi = 0; mi < 8; ++mi) {
#pragma unroll
    for (int ni = 0; ni < 4; ++ni) {
#pragma unroll
      for (int r = 0; r < 4; ++r) {
        int m = m0 + wr * 128 + mi * 16 + g4 * 4 + r;
        int n = n0 + wc * 64 + ni * 16 + l16;
        if (m < M_) {
          float vv = acc[mi][ni][r];
          if (EPI == 2) {
            ((float*)Cout)[(size_t)m * N + n] = vv;
          } else {
            int b = m / S_, pos = m % S_;
            ushort hv = f2bf(vv * oscale);
            ((ushort*)Cout)[(((size_t)b * NH + (n >> 6)) * SP + pos) * 64 + (n & 63)] = hv;
          }
        }
      }
    }
  }
}

// ---------------- fused K+V projection GEMMs (128x128, f32 A reg-staged) ----------------
__global__ __launch_bounds__(256)
void kvproj(const float* __restrict__ key, const float* __restrict__ value,
            const ushort* __restrict__ wkT, const ushort* __restrict__ wvT,
            ushort* __restrict__ kp, ushort* __restrict__ vp) {
  const int K = 1024, NK = 32;
  __shared__ alignas(16) ushort sA[2][128 * 32];
  __shared__ alignas(16) ushort sB[2][128 * 32];
  const int tid = threadIdx.x;
  const int lane = tid & 63, w = tid >> 6;

  const int nwg = gridDim.x;                       // 484
  const int qq = nwg >> 3, rr = nwg & 7;
  const int x = blockIdx.x & 7, seq = blockIdx.x >> 3;
  const int logical = x * qq + (x < rr ? x : rr) + seq;
  const bool isV = logical >= 242;
  const int l2 = isV ? logical - 242 : logical;
  const int m0 = (l2 >> 1) * 128;
  const int n0 = (l2 & 1) * 128;
  const float* Ain = isV ? value : key;
  const ushort* BT = isV ? wvT : wkT;
  ushort* Cout = isV ? vp : kp;

  const int srow = w * 32 + (lane >> 2);
  const int scol = ((lane & 3) ^ ((lane >> 3) & 3)) * 8;
  const ushort* gB0 = BT + (size_t)(n0 + srow) * K + scol;
  const int dstB = srow * 32 + (lane & 3) * 8;

  const int arow = w * 32 + (lane >> 1);
  const int acol = (lane & 1) * 16;
  const int sw = (lane >> 2) & 3;
  const int ag0 = (2 * (lane & 1)) ^ sw;
  const int ag1 = (2 * (lane & 1) + 1) ^ sw;
  const float* gA0f = Ain + (size_t)(m0 + arow) * K + acol;

  const int wr = w >> 1, wc = w & 1;
  const int g4 = lane >> 4, l16 = lane & 15;
  const int rsw = (l16 >> 1) & 3;
  const int aoff = (wr * 64 + l16) * 32 + 8 * (g4 ^ rsw);
  const int boff = (wc * 64 + l16) * 32 + 8 * (g4 ^ rsw);

  f32x4 acc[4][4] = {};
  float4 fA0, fA1, fA2, fA3;

  auto issueA = [&](int kt) {
    const float4* p = (const float4*)(gA0f + kt * 32);
    fA0 = p[0]; fA1 = p[1]; fA2 = p[2]; fA3 = p[3];
  };
  auto writeA = [&](int buf) {
    unsigned d0 = cvt_pk_bf16(fA0.x, fA0.y), d1 = cvt_pk_bf16(fA0.z, fA0.w);
    unsigned d2 = cvt_pk_bf16(fA1.x, fA1.y), d3 = cvt_pk_bf16(fA1.z, fA1.w);
    unsigned d4 = cvt_pk_bf16(fA2.x, fA2.y), d5 = cvt_pk_bf16(fA2.z, fA2.w);
    unsigned d6 = cvt_pk_bf16(fA3.x, fA3.y), d7 = cvt_pk_bf16(fA3.z, fA3.w);
    ushort* base = &sA[buf][arow * 32];
    uintx4 q0 = {d0, d1, d2, d3}, q1 = {d4, d5, d6, d7};
    *(uintx4*)(base + ag0 * 8) = q0;
    *(uintx4*)(base + ag1 * 8) = q1;
  };

  issueA(0);
  GLOAD_LDS16(gB0,          &sB[0][dstB]);
  GLOAD_LDS16(gB0 + 16 * K, &sB[0][dstB + 16 * 32]);
  writeA(0);

  for (int kt = 0; kt < NK; ++kt) {
    __syncthreads();
    const int nb = (kt + 1) & 1;
    if (kt + 1 < NK) {
      const ushort* gb = gB0 + (kt + 1) * 32;
      GLOAD_LDS16(gb,          &sB[nb][dstB]);
      GLOAD_LDS16(gb + 16 * K, &sB[nb][dstB + 16 * 32]);
      issueA(kt + 1);
    }
    const ushort* pa = &sA[kt & 1][aoff];
    const ushort* pb = &sB[kt & 1][boff];
    short8 af[4], bf[4];
#pragma unroll
    for (int i = 0; i < 4; ++i) {
      af[i] = *(const short8*)(pa + i * 16 * 32);
      bf[i] = *(const short8*)(pb + i * 16 * 32);
    }
#pragma unroll
    for (int mi = 0; mi < 4; ++mi)
#pragma unroll
      for (int ni = 0; ni < 4; ++ni)
        acc[mi][ni] = __builtin_amdgcn_mfma_f32_16x16x32_bf16(af[mi], bf[ni], acc[mi][ni], 0, 0, 0);
    if (kt + 1 < NK) writeA(nb);
  }

#pragma unroll
  for (int mi = 0; mi < 4; ++mi) {
#pragma unroll
    for (int ni = 0; ni < 4; ++ni) {
#pragma unroll
      for (int r = 0; r < 4; ++r) {
        int m = m0 + wr * 64 + mi * 16 + g4 * 4 + r;
        int n = n0 + wc * 64 + ni * 16 + l16;
        float vv = acc[mi][ni][r];
        int b = m / S_, pos = m % S_;
        if (!isV) {
          int dd = (n & 63) ^ ((pos & 7) << 3);
          Cout[(((size_t)b * 4 + (n >> 6)) * SP + pos) * 64 + dd] = f2bf(vv);
        } else {
          int local = pos & 31;
          int j = (local < 16) ? (2 * local) : (2 * local - 31);
          int pf_ = (pos & ~31) | (j ^ ((n & 3) << 3));
          Cout[(((size_t)b * 4 + (n >> 6)) * 64 + (n & 63)) * SP + pf_] = f2bf(vv);
        }
      }
    }
  }
}

// ---------------- fused GQA attention: 32 q-rows per wave, shared K/V frags ----------------
// grid 2048 (XCD-swizzled), block = 4 waves x 32 rows = 128 q-rows.
// Each wave: two 16-row sub-tiles share K-frag and V-frag LDS reads (2x amortization).
__global__ __launch_bounds__(256)
void attn_kernel(const ushort* __restrict__ qp, const ushort* __restrict__ kp,
                 const ushort* __restrict__ vpT, const float* __restrict__ rel,
                 ushort* __restrict__ ao) {
  __shared__ float2 sBiasP[1056];                 // (b[i], b[i+16]) pairs, +32 guard
  __shared__ alignas(16) ushort sK[2][32 * 64];
  __shared__ alignas(16) ushort sV[2][64 * 32];
  __shared__ alignas(16) ushort sP[4][32 * 40];
  const int tid = threadIdx.x;
  const int blk = blockIdx.x;
  const int logical = (blk & 7) * 256 + (blk >> 3);     // bijective (2048 = 8*256)
  const int qt = logical & 3, head = (logical >> 2) & 15, b = logical >> 6;
  const int g = head >> 2;
  const float LOG2E = 1.44269504f;
  for (int t = tid; t < 1056; t += 256) {
    float b0 = (t >= 32 && t < 999) ? rel[(t - 32) * 16 + head] * LOG2E : -1e30f;
    int t2 = t + 16;
    float b1 = (t2 >= 32 && t2 < 999) ? rel[(t2 - 32) * 16 + head] * LOG2E : -1e30f;
    sBiasP[t] = make_float2(b0, b1);
  }

  const int lane = tid & 63, w = tid >> 6;
  const int g4 = lane >> 4, l16 = lane & 15;
  const int qw = qt * 128 + w * 32;

  const ushort* qbA = qp + (((size_t)b * NH + head) * SP + qw + l16) * 64;
  const ushort* qbB = qbA + 16 * 64;
  short8 qf0a = *(const short8*)(qbA + 8 * g4);
  short8 qf1a = *(const short8*)(qbA + 32 + 8 * g4);
  short8 qf0b = *(const short8*)(qbB + 8 * g4);
  short8 qf1b = *(const short8*)(qbB + 32 + 8 * g4);

  const ushort* kSrc = kp  + ((size_t)b * 4 + g) * SP * 64 + (tid >> 3) * 64 + (tid & 7) * 8;
  const ushort* vSrc = vpT + ((size_t)b * 4 + g) * 64 * SP + (tid >> 2) * SP + (tid & 3) * 8;

  f32x4 accA[4] = {}, accB[4] = {};
  float psA[4] = {0.f, 0.f, 0.f, 0.f}, psB[4] = {0.f, 0.f, 0.f, 0.f};
  const int ibA = l16 - (qw + g4 * 4) + 515;      // pair-table idx (guard +32)
  const int ibB = ibA - 16;
  ushort* sPw = &sP[w][0];

  const int kswz  = (l16 & 7) << 3;
  const int kOff0 = l16 * 64 + ((8 * g4) ^ kswz);
  const int kOff1 = l16 * 64 + ((32 + 8 * g4) ^ kswz);
  const int vOff  = l16 * 32 + 8 * (g4 ^ (l16 & 3));

  GLOAD_LDS16(kSrc, &sK[0][w * 512]);
  GLOAD_LDS16(vSrc, &sV[0][w * 512]);

  for (int kt = 0; kt < 16; ++kt) {
    __syncthreads();
    if (kt + 1 < 16) {
      GLOAD_LDS16(kSrc + (kt + 1) * 2048, &sK[(kt + 1) & 1][w * 512]);
      GLOAD_LDS16(vSrc + (kt + 1) * 32,   &sV[(kt + 1) & 1][w * 512]);
    }
    const int k0 = kt * 32;
    // paired bias reads -> MFMA C-init (bias added by matrix pipe)
    float2 a0 = sBiasP[ibA + k0],     a1 = sBiasP[ibA + k0 - 1];
    float2 a2 = sBiasP[ibA + k0 - 2], a3 = sBiasP[ibA + k0 - 3];
    float2 c0 = sBiasP[ibB + k0],     c1 = sBiasP[ibB + k0 - 1];
    float2 c2 = sBiasP[ibB + k0 - 2], c3 = sBiasP[ibB + k0 - 3];
    f32x4 s0a = {a0.x, a1.x, a2.x, a3.x}, s1a = {a0.y, a1.y, a2.y, a3.y};
    f32x4 s0b = {c0.x, c1.x, c2.x, c3.x}, s1b = {c0.y, c1.y, c2.y, c3.y};

    const ushort* sk = &sK[kt & 1][0];
    const ushort* sv = &sV[kt & 1][0];
    short8 kf0 = *(const short8*)(sk + kOff0);
    short8 kf1 = *(const short8*)(sk + kOff1);
    short8 kf2 = *(const short8*)(sk + 1024 + kOff0);
    short8 kf3 = *(const short8*)(sk + 1024 + kOff1);
    s0a = __builtin_amdgcn_mfma_f32_16x16x32_bf16(qf0a, kf0, s0a, 0, 0, 0);
    s0a = __builtin_amdgcn_mfma_f32_16x16x32_bf16(qf1a, kf1, s0a, 0, 0, 0);
    s1a = __builtin_amdgcn_mfma_f32_16x16x32_bf16(qf0a, kf2, s1a, 0, 0, 0);
    s1a = __builtin_amdgcn_mfma_f32_16x16x32_bf16(qf1a, kf3, s1a, 0, 0, 0);
    s0b = __builtin_amdgcn_mfma_f32_16x16x32_bf16(qf0b, kf0, s0b, 0, 0, 0);
    s0b = __builtin_amdgcn_mfma_f32_16x16x32_bf16(qf1b, kf1, s0b, 0, 0, 0);
    s1b = __builtin_amdgcn_mfma_f32_16x16x32_bf16(qf0b, kf2, s1b, 0, 0, 0);
    s1b = __builtin_amdgcn_mfma_f32_16x16x32_bf16(qf1b, kf3, s1b, 0, 0, 0);

#pragma unroll
    for (int r = 0; r < 4; ++r) {
      float p0 = __builtin_amdgcn_exp2f(s0a[r]);
      float p1 = __builtin_amdgcn_exp2f(s1a[r]);
      float u0 = __builtin_amdgcn_exp2f(s0b[r]);
      float u1 = __builtin_amdgcn_exp2f(s1b[r]);
      if (kt == 15) {                       // mask BEFORE store: pad P == 0 exactly
        bool m0v = (k0 + l16 < S_), m1v = (k0 + 16 + l16 < S_);
        p0 = m0v ? p0 : 0.f;  p1 = m1v ? p1 : 0.f;
        u0 = m0v ? u0 : 0.f;  u1 = m1v ? u1 : 0.f;
      }
      psA[r] += p0 + p1;
      psB[r] += u0 + u1;
      *(unsigned*)(sPw + (g4 * 4 + r) * 40 + 2 * l16)        = cvt_pk_bf16(p0, p1);
      *(unsigned*)(sPw + (16 + g4 * 4 + r) * 40 + 2 * l16)   = cvt_pk_bf16(u0, u1);
    }
    short8 pfA = *(const short8*)(sPw + l16 * 40 + 8 * g4);
    short8 pfB = *(const short8*)(sPw + (16 + l16) * 40 + 8 * g4);
#pragma unroll
    for (int nt = 0; nt < 4; ++nt) {
      short8 vf = *(const short8*)(sv + vOff + nt * 512);    // shared by both sub-tiles
      accA[nt] = __builtin_amdgcn_mfma_f32_16x16x32_bf16(pfA, vf, accA[nt], 0, 0, 0);
      accB[nt] = __builtin_amdgcn_mfma_f32_16x16x32_bf16(pfB, vf, accB[nt], 0, 0, 0);
    }
  }

#pragma unroll
  for (int off = 1; off < 16; off <<= 1) {
#pragma unroll
    for (int r = 0; r < 4; ++r) {
      psA[r] += __shfl_xor(psA[r], off, 64);
      psB[r] += __shfl_xor(psB[r], off, 64);
    }
  }

#pragma unroll
  for (int r = 0; r < 4; ++r) {
    int qa = qw + g4 * 4 + r;
    if (qa < S_) {
      float inv = 1.f / psA[r];
#pragma unroll
      for (int nt = 0; nt < 4; ++nt)
        ao[((size_t)b * S_ + qa) * 1024 + head * 64 + nt * 16 + l16] = f2bf(accA[nt][r] * inv);
    }
    int qb2 = qa + 16;
    if (qb2 < S_) {
      float inv = 1.f / psB[r];
#pragma unroll
      for (int nt = 0; nt < 4; ++nt)
        ao[((size_t)b * S_ + qb2) * 1024 + head * 64 + nt * 16 + l16] = f2bf(accB[nt][r] * inv);
    }
  }
}

extern "C" void kernel_launch(void* const* d_in, const int* in_sizes, int n_in,
                              void* d_out, int out_size, void* d_ws, size_t ws_size,
                              hipStream_t stream) {
  const float* query = (const float*)d_in[0];
  const float* key   = (const float*)d_in[1];
  const float* value = (const float*)d_in[2];
  const float* Wq    = (const float*)d_in[3];
  const float* Wk    = (const float*)d_in[4];
  const float* Wv    = (const float*)d_in[5];
  const float* Wo    = (const float*)d_in[6];
  const float* rel   = (const float*)d_in[7];

  char* ws = (char*)d_ws;
  size_t off = 0;
  auto alloc = [&](size_t bytes) { char* p = ws + off; off += (bytes + 255) & ~(size_t)255; return p; };

  const size_t MEelems = (size_t)M_ * E_;             // 15,859,712
  ushort* qb  = (ushort*)alloc(MEelems * 2);          // query in bf16
  ushort* wqT = (ushort*)alloc((size_t)1024 * 1024 * 2);
  ushort* wkT = (ushort*)alloc((size_t)256 * 1024 * 2);
  ushort* wvT = (ushort*)alloc((size_t)256 * 1024 * 2);
  ushort* woT = (ushort*)alloc((size_t)1024 * 1024 * 2);
  ushort* qp  = (ushort*)alloc((size_t)B_ * NH * SP * 64 * 2);   // 32 MB
  ushort* kp  = (ushort*)alloc((size_t)B_ * 4 * SP * 64 * 2);    // 8 MB
  ushort* vp  = (ushort*)alloc((size_t)B_ * 4 * 64 * SP * 2);    // 8 MB
  ushort* ao  = (ushort*)alloc(MEelems * 2);

  cvt_f32_bf16<<<2048, 256, 0, stream>>>(query, qb, (int)(MEelems / 4));

  transpose_all<<<2560, 256, 0, stream>>>(Wq, Wk, Wv, Wo, wqT, wkT, wvT, woT);

  const float QSCALE = 0.125f * 1.44269504f;   // fold 1/sqrt(D) and log2e into q
  gemm_cnt256<0><<<244, 512, 0, stream>>>(qb, wqT, qp, QSCALE);
  kvproj<<<484, 256, 0, stream>>>(key, value, wkT, wvT, kp, vp);

  attn_kernel<<<2048, 256, 0, stream>>>(qp, kp, vp, rel, ao);

  gemm_cnt256<2><<<244, 512, 0, stream>>>(ao, woT, d_out, 1.0f);
}